// Round 1
// baseline (215.672 us; speedup 1.0000x reference)
//
#include <hip/hip_runtime.h>
#include <math.h>

// ---------------------------------------------------------------------------
// VQCodebook forward, MI355X.
// B=256, D=128, K=8192. All fp32.
//
// Pipeline:
//  A: conv1(3->64)+ReLU fused with window-sum stats -> S[b][64][9]  (no h1 in HBM)
//  P: precompute stage-1 decoder config weights Wcfg[9][64][128]
//  B1: z[b][oc] = b2 + w2 . S  (inner 576)
//  B2: VQ partial argmin (4 batches x 1024 codes per block)
//  B3: final argmin, z_q, losses, indices
//  C: decoder as config-GEMMs (9 -> 25 -> 49 configs) + expand + tanh
// ---------------------------------------------------------------------------

// ------------------ Kernel A: conv1 + relu + stats ------------------
__global__ __launch_bounds__(256) void k_conv1_stats(
    const float* __restrict__ patch, const float* __restrict__ w1,
    const float* __restrict__ b1, float* __restrict__ S)
{
    __shared__ float lds[3 * 66 * 68];  // zero-padded patch, 53856 B
    const int b = blockIdx.x;
    const int tid = threadIdx.x;

    for (int i = tid; i < 3 * 66 * 68; i += 256) lds[i] = 0.f;
    __syncthreads();
    const float* pb = patch + (size_t)b * 3 * 64 * 64;
    for (int i = tid; i < 3 * 64 * 64; i += 256) {
        int c = i >> 12, rem = i & 4095;
        int y = rem >> 6, x = rem & 63;
        lds[(c * 66 + y + 1) * 68 + (x + 1)] = pb[i];
    }
    __syncthreads();

    const int ch = tid & 63;   // output channel
    const int q  = tid >> 6;   // row group (16 rows each)

    float w[3][3][3];
#pragma unroll
    for (int ic = 0; ic < 3; ++ic)
#pragma unroll
        for (int ky = 0; ky < 3; ++ky)
#pragma unroll
            for (int kx = 0; kx < 3; ++kx)
                w[ic][ky][kx] = w1[((ch * 3 + ic) * 3 + ky) * 3 + kx];
    const float bias = b1[ch];

    float T = 0, r0 = 0, r63 = 0, c0 = 0, c63 = 0;
    float h00 = 0, h063 = 0, h630 = 0, h6363 = 0;

    for (int y = q * 16; y < q * 16 + 16; ++y) {
        for (int xc = 0; xc < 16; ++xc) {
            float a0 = bias, a1 = bias, a2 = bias, a3 = bias;
#pragma unroll
            for (int ic = 0; ic < 3; ++ic) {
#pragma unroll
                for (int ky = 0; ky < 3; ++ky) {
                    const float* p = &lds[(ic * 66 + y + ky) * 68 + xc * 4];
                    float4 va = *(const float4*)p;
                    float2 vb = *(const float2*)(p + 4);
                    float win[6] = {va.x, va.y, va.z, va.w, vb.x, vb.y};
#pragma unroll
                    for (int kx = 0; kx < 3; ++kx) {
                        float wv = w[ic][ky][kx];
                        a0 = fmaf(wv, win[kx + 0], a0);
                        a1 = fmaf(wv, win[kx + 1], a1);
                        a2 = fmaf(wv, win[kx + 2], a2);
                        a3 = fmaf(wv, win[kx + 3], a3);
                    }
                }
            }
            a0 = fmaxf(a0, 0.f); a1 = fmaxf(a1, 0.f);
            a2 = fmaxf(a2, 0.f); a3 = fmaxf(a3, 0.f);
            float rs = a0 + a1 + a2 + a3;
            T += rs;
            if (y == 0)  { r0  += rs; if (xc == 0) h00  = a0; if (xc == 15) h063  = a3; }
            if (y == 63) { r63 += rs; if (xc == 0) h630 = a0; if (xc == 15) h6363 = a3; }
            if (xc == 0)  c0  += a0;
            if (xc == 15) c63 += a3;
        }
    }
    __syncthreads();  // done reading patch; reuse lds for reduction

    float* red = lds;
    float st[9] = {T, r0, r63, c0, c63, h00, h063, h630, h6363};
#pragma unroll
    for (int s = 0; s < 9; ++s) red[(s * 4 + q) * 64 + ch] = st[s];
    __syncthreads();

    if (tid < 64) {
        float f[9];
#pragma unroll
        for (int s = 0; s < 9; ++s)
            f[s] = red[(s * 4 + 0) * 64 + tid] + red[(s * 4 + 1) * 64 + tid]
                 + red[(s * 4 + 2) * 64 + tid] + red[(s * 4 + 3) * 64 + tid];
        float Tt = f[0], R0 = f[1], R63 = f[2], C0 = f[3], C63 = f[4];
        float H00 = f[5], H063 = f[6], H630 = f[7], H6363 = f[8];
        float* Sp = S + ((size_t)b * 64 + tid) * 9;
#pragma unroll
        for (int ky = 0; ky < 3; ++ky) {
            float rex = (ky == 0) ? R63 : (ky == 2 ? R0 : 0.f);
#pragma unroll
            for (int kx = 0; kx < 3; ++kx) {
                float cex = (kx == 0) ? C63 : (kx == 2 ? C0 : 0.f);
                float corner = 0.f;
                if (ky == 0 && kx == 0) corner = H6363;
                if (ky == 0 && kx == 2) corner = H630;
                if (ky == 2 && kx == 0) corner = H063;
                if (ky == 2 && kx == 2) corner = H00;
                Sp[ky * 3 + kx] = (Tt - rex - cex + corner) * (1.f / 4096.f);
            }
        }
    }
}

// ------------------ Kernel P: stage-1 decoder config weights ------------------
// Wcfg[(cfg*64+o)*128+i] = sum over ky' in R(cy), kx' in R(cx) of dec_w1[i][o][ky'][kx']
// R(0)={0,1}, R(1)={0,1,2}, R(2)={1,2}   (cfg = cy*3+cx)
__global__ __launch_bounds__(256) void k_wcfg(const float* __restrict__ dw1,
                                              float* __restrict__ Wcfg)
{
    int gid = blockIdx.x * 256 + threadIdx.x;   // 73728
    int cfg = gid >> 13;
    int o = (gid >> 7) & 63;
    int i = gid & 127;
    int cy = cfg / 3, cx = cfg % 3;
    int ylo = (cy == 2) ? 1 : 0, yhi = (cy == 0) ? 1 : 2;
    int xlo = (cx == 2) ? 1 : 0, xhi = (cx == 0) ? 1 : 2;
    const float* wp = dw1 + ((size_t)i * 64 + o) * 9;
    float s = 0.f;
    for (int ky = ylo; ky <= yhi; ++ky)
        for (int kx = xlo; kx <= xhi; ++kx)
            s += wp[ky * 3 + kx];
    Wcfg[gid] = s;
}

// ------------------ Kernel B1: z = b2 + w2 . S ------------------
__global__ __launch_bounds__(256) void k_zgemm(
    const float* __restrict__ S, const float* __restrict__ w2,
    const float* __restrict__ b2, float* __restrict__ z)
{
    int gid = blockIdx.x * 256 + threadIdx.x;  // 32768
    int b = gid >> 7, oc = gid & 127;
    const float4* Sv = (const float4*)(S + (size_t)b * 576);
    const float4* Wv = (const float4*)(w2 + (size_t)oc * 576);
    float acc = b2[oc];
    for (int t = 0; t < 144; ++t) {
        float4 s4 = Sv[t], w4 = Wv[t];
        acc = fmaf(s4.x, w4.x, acc);
        acc = fmaf(s4.y, w4.y, acc);
        acc = fmaf(s4.z, w4.z, acc);
        acc = fmaf(s4.w, w4.w, acc);
    }
    z[gid] = acc;
}

// ------------------ Kernel B2: VQ partial argmin ------------------
// grid 512: bg = blockIdx>>3 (4 batches), kc = blockIdx&7 (1024 codes)
__global__ __launch_bounds__(256) void k_vq_partial(
    const float* __restrict__ z, const float* __restrict__ emb,
    float* __restrict__ pd2, int* __restrict__ pidx)
{
    __shared__ float zsh[4 * 128];
    __shared__ float bd[256];
    __shared__ int   bis[256];
    int tid = threadIdx.x;
    int bg = blockIdx.x >> 3;
    int kc = blockIdx.x & 7;
    int b0 = bg * 4;
    for (int i = tid; i < 512; i += 256) zsh[i] = z[b0 * 128 + i];
    __syncthreads();

    float best[4] = {1e30f, 1e30f, 1e30f, 1e30f};
    int bidx[4] = {0, 0, 0, 0};
    int kbase = kc * 1024 + tid;

    const float4* zv = (const float4*)zsh;
    float acc[4][4];
#pragma unroll
    for (int j = 0; j < 4; ++j)
#pragma unroll
        for (int bb = 0; bb < 4; ++bb) acc[j][bb] = 0.f;

    for (int t = 0; t < 32; ++t) {
        float4 e[4];
#pragma unroll
        for (int j = 0; j < 4; ++j)
            e[j] = *(const float4*)(emb + (size_t)(kbase + 256 * j) * 128 + t * 4);
#pragma unroll
        for (int bb = 0; bb < 4; ++bb) {
            float4 zz = zv[bb * 32 + t];
#pragma unroll
            for (int j = 0; j < 4; ++j) {
                float dx = zz.x - e[j].x, dy = zz.y - e[j].y;
                float dz = zz.z - e[j].z, dw = zz.w - e[j].w;
                acc[j][bb] = fmaf(dx, dx, fmaf(dy, dy, fmaf(dz, dz, fmaf(dw, dw, acc[j][bb]))));
            }
        }
    }
#pragma unroll
    for (int j = 0; j < 4; ++j) {
        int k = kbase + 256 * j;
#pragma unroll
        for (int bb = 0; bb < 4; ++bb)
            if (acc[j][bb] < best[bb]) { best[bb] = acc[j][bb]; bidx[bb] = k; }
    }

    for (int bb = 0; bb < 4; ++bb) {
        bd[tid] = best[bb]; bis[tid] = bidx[bb];
        __syncthreads();
        for (int s = 128; s > 0; s >>= 1) {
            if (tid < s) {
                float dv = bd[tid + s]; int iv = bis[tid + s];
                if (dv < bd[tid] || (dv == bd[tid] && iv < bis[tid])) {
                    bd[tid] = dv; bis[tid] = iv;
                }
            }
            __syncthreads();
        }
        if (tid == 0) {
            pd2[(b0 + bb) * 8 + kc] = bd[0];
            pidx[(b0 + bb) * 8 + kc] = bis[0];
        }
        __syncthreads();
    }
}

// ------------------ Kernel B3: final argmin, z_q, losses, indices ------------------
__global__ __launch_bounds__(256) void k_vq_final(
    const float* __restrict__ z, const float* __restrict__ emb,
    const float* __restrict__ pd2, const int* __restrict__ pidx,
    float* __restrict__ zq, float* __restrict__ out)
{
    __shared__ float red[256];
    int b = threadIdx.x;
    float best = 1e30f; int bi = 0x7fffffff;
    for (int kc = 0; kc < 8; ++kc) {
        float d = pd2[b * 8 + kc]; int ix = pidx[b * 8 + kc];
        if (d < best || (d == best && ix < bi)) { best = d; bi = ix; }
    }
    out[3145730 + b] = (float)bi;
    float ss = 0.f;
    const float* e = emb + (size_t)bi * 128;
    const float* zb = z + b * 128;
    float* zqb = zq + b * 128;
    for (int d = 0; d < 128; ++d) {
        float ev = e[d]; zqb[d] = ev;
        float df = ev - zb[d];
        ss = fmaf(df, df, ss);
    }
    red[b] = ss;
    __syncthreads();
    for (int s = 128; s > 0; s >>= 1) {
        if (b < s) red[b] += red[b + s];
        __syncthreads();
    }
    if (b == 0) {
        float l = red[0] / 32768.f;
        out[3145728] = l;  // codebook_loss
        out[3145729] = l;  // commitment_loss (identical forward value)
    }
}

// ------------------ Kernel C: decoder via config GEMMs + expand ------------------
__global__ __launch_bounds__(256) void k_decode(
    const float* __restrict__ zq, const float* __restrict__ Wcfg,
    const float* __restrict__ db1, const float* __restrict__ dw2,
    const float* __restrict__ db2, const float* __restrict__ dw3,
    const float* __restrict__ db3, float* __restrict__ out)
{
    __shared__ float zsh[128];
    __shared__ float d1e[64][10];    // 9 cfgs + zero slot
    __shared__ float part[256 * 25];
    __shared__ float d2e[64][26];    // 25 cfgs + zero slot
    __shared__ float o3[3 * 49];

    const int b = blockIdx.x, tid = threadIdx.x;
    if (tid < 128) zsh[tid] = zq[b * 128 + tid];
    if (tid < 64) { d1e[tid][9] = 0.f; d2e[tid][25] = 0.f; }
    __syncthreads();

    // ---- stage 1: d1cfg[o][cfg] = relu(db1 + Wcfg[cfg][o][:] . zq) ----
    for (int id = tid; id < 576; id += 256) {
        int o = id / 9, cfg = id % 9;
        const float4* wv = (const float4*)(Wcfg + ((size_t)cfg * 64 + o) * 128);
        const float4* zv = (const float4*)zsh;
        float acc = db1[o];
        for (int t = 0; t < 32; ++t) {
            float4 w4 = wv[t], z4 = zv[t];
            acc = fmaf(w4.x, z4.x, acc);
            acc = fmaf(w4.y, z4.y, acc);
            acc = fmaf(w4.z, z4.z, acc);
            acc = fmaf(w4.w, z4.w, acc);
        }
        d1e[o][cfg] = fmaxf(acc, 0.f);
    }
    __syncthreads();

    // ---- stage 2: 25 cfgs; thread = (o, i-subrange) ----
    {
        const int TY5[5][3] = {{-1,0,1},{0,1,1},{1,1,1},{1,1,2},{1,2,-1}};
        int o = tid >> 2, isub = tid & 3;
        float acc[25];
#pragma unroll
        for (int c = 0; c < 25; ++c) acc[c] = 0.f;
        for (int ii = 0; ii < 16; ++ii) {
            int i = isub + ii * 4;
            float d1v[10];
#pragma unroll
            for (int t = 0; t < 9; ++t) d1v[t] = d1e[i][t];
            d1v[9] = 0.f;
            float w9[9];
            const float* wp = dw2 + ((size_t)i * 64 + o) * 9;
#pragma unroll
            for (int t = 0; t < 9; ++t) w9[t] = wp[t];
#pragma unroll
            for (int cy = 0; cy < 5; ++cy) {
#pragma unroll
                for (int ky = 0; ky < 3; ++ky) {
                    int ty = TY5[cy][ky];
                    if (ty < 0) continue;
#pragma unroll
                    for (int cx = 0; cx < 5; ++cx) {
#pragma unroll
                        for (int kx = 0; kx < 3; ++kx) {
                            int tx = TY5[cx][kx];
                            if (tx < 0) continue;
                            acc[cy * 5 + cx] = fmaf(w9[(2 - ky) * 3 + (2 - kx)],
                                                    d1v[ty * 3 + tx], acc[cy * 5 + cx]);
                        }
                    }
                }
            }
        }
#pragma unroll
        for (int c = 0; c < 25; ++c) part[(o * 4 + isub) * 25 + c] = acc[c];
    }
    __syncthreads();
    for (int id = tid; id < 1600; id += 256) {
        int o = id / 25, c = id % 25;
        float v = part[(o * 4 + 0) * 25 + c] + part[(o * 4 + 1) * 25 + c]
                + part[(o * 4 + 2) * 25 + c] + part[(o * 4 + 3) * 25 + c] + db2[o];
        d2e[o][c] = fmaxf(v, 0.f);
    }
    __syncthreads();

    // ---- stage 3: 49 cfgs x 3 channels ----
    if (tid < 147) {
        const int TY7[7][3] = {{-1,0,1},{0,1,2},{1,2,2},{2,2,2},{2,2,3},{2,3,4},{3,4,-1}};
        int c3 = tid / 49, cc = tid % 49, cy = cc / 7, cx = cc % 7;
        float acc = db3[c3];
        for (int i = 0; i < 64; ++i) {
            const float* wp = dw3 + ((size_t)i * 3 + c3) * 9;
#pragma unroll
            for (int ky = 0; ky < 3; ++ky) {
                int ty = TY7[cy][ky];
#pragma unroll
                for (int kx = 0; kx < 3; ++kx) {
                    int tx = TY7[cx][kx];
                    int t = (ty < 0 || tx < 0) ? 25 : ty * 5 + tx;
                    acc = fmaf(wp[(2 - ky) * 3 + (2 - kx)], d2e[i][t], acc);
                }
            }
        }
        o3[c3 * 49 + cc] = tanhf(acc);
    }
    __syncthreads();

    // ---- expand + write ----
    float* ob = out + (size_t)b * 3 * 4096;
    for (int id = tid; id < 3 * 4096; id += 256) {
        int c = id >> 12, rem = id & 4095, y = rem >> 6, x = rem & 63;
        int ry = (y <= 3) ? y : (y >= 60 ? y - 57 : 3);
        int rx = (x <= 3) ? x : (x >= 60 ? x - 57 : 3);
        ob[id] = o3[c * 49 + ry * 7 + rx];
    }
}

// ---------------------------------------------------------------------------
extern "C" void kernel_launch(void* const* d_in, const int* in_sizes, int n_in,
                              void* d_out, int out_size, void* d_ws, size_t ws_size,
                              hipStream_t stream)
{
    const float* patch  = (const float*)d_in[0];
    const float* enc_w1 = (const float*)d_in[1];
    const float* enc_b1 = (const float*)d_in[2];
    const float* enc_w2 = (const float*)d_in[3];
    const float* enc_b2 = (const float*)d_in[4];
    const float* emb    = (const float*)d_in[5];
    const float* dec_w1 = (const float*)d_in[6];
    const float* dec_b1 = (const float*)d_in[7];
    const float* dec_w2 = (const float*)d_in[8];
    const float* dec_b2 = (const float*)d_in[9];
    const float* dec_w3 = (const float*)d_in[10];
    const float* dec_b3 = (const float*)d_in[11];

    float* out = (float*)d_out;
    float* ws  = (float*)d_ws;

    float* S    = ws;             // 256*64*9 = 147456
    float* z    = ws + 147456;    // 32768
    float* zq   = ws + 180224;    // 32768
    float* pd2  = ws + 212992;    // 2048 (use 4096 slack)
    int*   pidx = (int*)(ws + 217088);  // 2048
    float* Wcfg = ws + 221184;    // 73728

    k_conv1_stats<<<dim3(256), dim3(256), 0, stream>>>(patch, enc_w1, enc_b1, S);
    k_wcfg<<<dim3(288), dim3(256), 0, stream>>>(dec_w1, Wcfg);
    k_zgemm<<<dim3(128), dim3(256), 0, stream>>>(S, enc_w2, enc_b2, z);
    k_vq_partial<<<dim3(512), dim3(256), 0, stream>>>(z, emb, pd2, pidx);
    k_vq_final<<<dim3(1), dim3(256), 0, stream>>>(z, emb, pd2, pidx, zq, out);
    k_decode<<<dim3(256), dim3(256), 0, stream>>>(zq, Wcfg, dec_b1, dec_w2, dec_b2,
                                                  dec_w3, dec_b3, out);
}

// Round 2
// 159.438 us; speedup vs baseline: 1.3527x; 1.3527x over previous
//
#include <hip/hip_runtime.h>
#include <math.h>

// ---------------------------------------------------------------------------
// VQCodebook forward, MI355X. B=256, D=128, K=8192, fp32.
//
//  A: conv1(3->64)+ReLU + window stats, 4 row-groups/batch -> pstat (grid 1024)
//  P: Wcfg (stage-1 decoder config weights) + ||e||^2      (grid 320)
//  Z: reduce pstat -> S -> z = b2 + w2.S                   (grid 256)
//  V1: VQ partial argmin over ||e||^2 - 2 z.e              (grid 1024)
//  V2: final argmin, z_q, losses, indices                  (grid 1)
//  D: decoder config-GEMMs (9 -> 25 -> 49) + expand + tanh (grid 256)
// ---------------------------------------------------------------------------

// ------------------ Kernel A: conv1 + relu + partial stats ------------------
__global__ __launch_bounds__(256) void k_conv1_stats(
    const float* __restrict__ patch, const float* __restrict__ w1,
    const float* __restrict__ b1, float* __restrict__ pstat)
{
    __shared__ float lds[3 * 18 * 68];  // 3672 floats = 14688 B
    const int blk = blockIdx.x;
    const int b = blk >> 2, rg = blk & 3;
    const int y0 = rg * 16;
    const int tid = threadIdx.x;

    const float* pb = patch + (size_t)b * 3 * 64 * 64;
    for (int i = tid; i < 3 * 18 * 68; i += 256) {
        int c = i / 1224, rem = i % 1224;
        int r = rem / 68, pc = rem % 68;
        int y = y0 + r - 1, x = pc - 1;
        float v = 0.f;
        if (y >= 0 && y < 64 && x >= 0 && x < 64)
            v = pb[(c << 12) + (y << 6) + x];
        lds[i] = v;
    }
    __syncthreads();

    const int ch = tid & 63;   // output channel
    const int q  = tid >> 6;   // 4 rows each

    float w[3][3][3];
#pragma unroll
    for (int ic = 0; ic < 3; ++ic)
#pragma unroll
        for (int ky = 0; ky < 3; ++ky)
#pragma unroll
            for (int kx = 0; kx < 3; ++kx)
                w[ic][ky][kx] = w1[((ch * 3 + ic) * 3 + ky) * 3 + kx];
    const float bias = b1[ch];

    float T = 0, r0 = 0, r63 = 0, c0 = 0, c63 = 0;
    float h00 = 0, h063 = 0, h630 = 0, h6363 = 0;

    for (int yl = q * 4; yl < q * 4 + 4; ++yl) {
        const int y = y0 + yl;
        for (int xc = 0; xc < 16; ++xc) {
            float a0 = bias, a1 = bias, a2 = bias, a3 = bias;
#pragma unroll
            for (int ic = 0; ic < 3; ++ic) {
#pragma unroll
                for (int ky = 0; ky < 3; ++ky) {
                    const float* p = &lds[(ic * 18 + yl + ky) * 68 + xc * 4];
                    float4 va = *(const float4*)p;
                    float2 vb = *(const float2*)(p + 4);
                    float win[6] = {va.x, va.y, va.z, va.w, vb.x, vb.y};
#pragma unroll
                    for (int kx = 0; kx < 3; ++kx) {
                        float wv = w[ic][ky][kx];
                        a0 = fmaf(wv, win[kx + 0], a0);
                        a1 = fmaf(wv, win[kx + 1], a1);
                        a2 = fmaf(wv, win[kx + 2], a2);
                        a3 = fmaf(wv, win[kx + 3], a3);
                    }
                }
            }
            a0 = fmaxf(a0, 0.f); a1 = fmaxf(a1, 0.f);
            a2 = fmaxf(a2, 0.f); a3 = fmaxf(a3, 0.f);
            float rs = a0 + a1 + a2 + a3;
            T += rs;
            if (y == 0)  { r0  += rs; if (xc == 0) h00  = a0; if (xc == 15) h063  = a3; }
            if (y == 63) { r63 += rs; if (xc == 0) h630 = a0; if (xc == 15) h6363 = a3; }
            if (xc == 0)  c0  += a0;
            if (xc == 15) c63 += a3;
        }
    }
    __syncthreads();  // reuse lds for reduction

    float* red = lds;
    float st[9] = {T, r0, r63, c0, c63, h00, h063, h630, h6363};
#pragma unroll
    for (int s = 0; s < 9; ++s) red[(s * 4 + q) * 64 + ch] = st[s];
    __syncthreads();

    if (tid < 64) {
        float* pp = pstat + (size_t)blk * 576;
#pragma unroll
        for (int s = 0; s < 9; ++s)
            pp[s * 64 + tid] = red[(s * 4 + 0) * 64 + tid] + red[(s * 4 + 1) * 64 + tid]
                             + red[(s * 4 + 2) * 64 + tid] + red[(s * 4 + 3) * 64 + tid];
    }
}

// ------------------ Kernel P: Wcfg + ||e||^2 ------------------
__global__ __launch_bounds__(256) void k_pre(
    const float* __restrict__ dw1, const float* __restrict__ emb,
    float* __restrict__ Wcfg, float* __restrict__ en2)
{
    int gid = blockIdx.x * 256 + threadIdx.x;
    if (gid < 73728) {
        int cfg = gid >> 13;
        int o = (gid >> 7) & 63;
        int i = gid & 127;
        int cy = cfg / 3, cx = cfg % 3;
        int ylo = (cy == 2) ? 1 : 0, yhi = (cy == 0) ? 1 : 2;
        int xlo = (cx == 2) ? 1 : 0, xhi = (cx == 0) ? 1 : 2;
        const float* wp = dw1 + ((size_t)i * 64 + o) * 9;
        float s = 0.f;
        for (int ky = ylo; ky <= yhi; ++ky)
            for (int kx = xlo; kx <= xhi; ++kx)
                s += wp[ky * 3 + kx];
        Wcfg[gid] = s;
    } else if (gid < 73728 + 8192) {
        int k = gid - 73728;
        const float4* e = (const float4*)(emb + (size_t)k * 128);
        float s = 0.f;
        for (int t = 0; t < 32; ++t) {
            float4 v = e[t];
            s = fmaf(v.x, v.x, fmaf(v.y, v.y, fmaf(v.z, v.z, fmaf(v.w, v.w, s))));
        }
        en2[k] = s;
    }
}

// ------------------ Kernel Z: stats reduce + S + z-GEMM ------------------
__global__ __launch_bounds__(256) void k_zred(
    const float* __restrict__ pstat, const float* __restrict__ w2,
    const float* __restrict__ b2, float* __restrict__ z)
{
    __shared__ float fst[576];                   // [s*64+ch]
    __shared__ __align__(16) float Ssh[576];     // [ch*9+tap]
    __shared__ float zp[256];
    const int b = blockIdx.x, tid = threadIdx.x;

    const float* pp = pstat + (size_t)b * 4 * 576;
    for (int i = tid; i < 576; i += 256)
        fst[i] = pp[i] + pp[i + 576] + pp[i + 1152] + pp[i + 1728];
    __syncthreads();

    if (tid < 64) {
        int ch = tid;
        float Tt   = fst[0 * 64 + ch], R0  = fst[1 * 64 + ch], R63 = fst[2 * 64 + ch];
        float C0   = fst[3 * 64 + ch], C63 = fst[4 * 64 + ch];
        float H00  = fst[5 * 64 + ch], H063 = fst[6 * 64 + ch];
        float H630 = fst[7 * 64 + ch], H6363 = fst[8 * 64 + ch];
#pragma unroll
        for (int ky = 0; ky < 3; ++ky) {
            float rex = (ky == 0) ? R63 : (ky == 2 ? R0 : 0.f);
#pragma unroll
            for (int kx = 0; kx < 3; ++kx) {
                float cex = (kx == 0) ? C63 : (kx == 2 ? C0 : 0.f);
                float corner = 0.f;
                if (ky == 0 && kx == 0) corner = H6363;
                if (ky == 0 && kx == 2) corner = H630;
                if (ky == 2 && kx == 0) corner = H063;
                if (ky == 2 && kx == 2) corner = H00;
                Ssh[ch * 9 + ky * 3 + kx] = (Tt - rex - cex + corner) * (1.f / 4096.f);
            }
        }
    }
    __syncthreads();

    const int oc = tid & 127, h = tid >> 7;
    const float4* Wv = (const float4*)(w2 + (size_t)oc * 576 + h * 288);
    const float4* Sv = (const float4*)(Ssh + h * 288);
    float acc = 0.f;
    for (int t = 0; t < 72; ++t) {
        float4 w4 = Wv[t], s4 = Sv[t];
        acc = fmaf(w4.x, s4.x, acc);
        acc = fmaf(w4.y, s4.y, acc);
        acc = fmaf(w4.z, s4.z, acc);
        acc = fmaf(w4.w, s4.w, acc);
    }
    zp[tid] = acc;
    __syncthreads();
    if (tid < 128) z[(size_t)b * 128 + tid] = b2[tid] + zp[tid] + zp[tid + 128];
}

// ------------------ Kernel V1: VQ partial argmin ------------------
// grid 1024: bg = blk>>4 (4 batches), kc = blk&15 (512 codes)
__global__ __launch_bounds__(256) void k_vq_partial(
    const float* __restrict__ z, const float* __restrict__ emb,
    const float* __restrict__ en2,
    float* __restrict__ pd2, int* __restrict__ pidx)
{
    __shared__ __align__(16) float zsh[512];
    __shared__ float wd[4][4];
    __shared__ int   wi[4][4];
    const int tid = threadIdx.x;
    const int bg = blockIdx.x >> 4, kc = blockIdx.x & 15;
    const int b0 = bg * 4;
    for (int i = tid; i < 512; i += 256) zsh[i] = z[(size_t)b0 * 128 + i];
    __syncthreads();

    const int k0 = kc * 512 + tid;
    const float4* zv = (const float4*)zsh;
    const float4* e0 = (const float4*)(emb + (size_t)k0 * 128);
    const float4* e1 = (const float4*)(emb + (size_t)(k0 + 256) * 128);

    float acc0[4] = {0, 0, 0, 0}, acc1[4] = {0, 0, 0, 0};
    for (int t = 0; t < 32; ++t) {
        float4 ea = e0[t], eb = e1[t];
#pragma unroll
        for (int bb = 0; bb < 4; ++bb) {
            float4 zz = zv[bb * 32 + t];
            acc0[bb] = fmaf(zz.x, ea.x, fmaf(zz.y, ea.y, fmaf(zz.z, ea.z, fmaf(zz.w, ea.w, acc0[bb]))));
            acc1[bb] = fmaf(zz.x, eb.x, fmaf(zz.y, eb.y, fmaf(zz.z, eb.z, fmaf(zz.w, eb.w, acc1[bb]))));
        }
    }
    const float E0 = en2[k0], E1 = en2[k0 + 256];

#pragma unroll
    for (int bb = 0; bb < 4; ++bb) {
        float da = E0 - 2.f * acc0[bb];
        float db = E1 - 2.f * acc1[bb];
        float d; int ix;
        if (da <= db) { d = da; ix = k0; } else { d = db; ix = k0 + 256; }
#pragma unroll
        for (int off = 32; off > 0; off >>= 1) {
            float od = __shfl_xor(d, off);
            int   oi = __shfl_xor(ix, off);
            if (od < d || (od == d && oi < ix)) { d = od; ix = oi; }
        }
        if ((tid & 63) == 0) { wd[bb][tid >> 6] = d; wi[bb][tid >> 6] = ix; }
    }
    __syncthreads();
    if (tid < 4) {
        int bb = tid;
        float d = wd[bb][0]; int ix = wi[bb][0];
#pragma unroll
        for (int wv = 1; wv < 4; ++wv) {
            float od = wd[bb][wv]; int oi = wi[bb][wv];
            if (od < d || (od == d && oi < ix)) { d = od; ix = oi; }
        }
        pd2[(b0 + bb) * 16 + kc] = d;
        pidx[(b0 + bb) * 16 + kc] = ix;
    }
}

// ------------------ Kernel V2: final argmin, z_q, losses, indices ------------------
__global__ __launch_bounds__(256) void k_vq_final(
    const float* __restrict__ z, const float* __restrict__ emb,
    const float* __restrict__ pd2, const int* __restrict__ pidx,
    float* __restrict__ zq, float* __restrict__ out)
{
    __shared__ float red[256];
    const int b = threadIdx.x;
    float best = 1e30f; int bi = 0x7fffffff;
    for (int kc = 0; kc < 16; ++kc) {
        float d = pd2[b * 16 + kc]; int ix = pidx[b * 16 + kc];
        if (d < best || (d == best && ix < bi)) { best = d; bi = ix; }
    }
    out[3145730 + b] = (float)bi;
    float ss = 0.f;
    const float4* e  = (const float4*)(emb + (size_t)bi * 128);
    const float4* zb = (const float4*)(z + (size_t)b * 128);
    float4* zqb = (float4*)(zq + (size_t)b * 128);
    for (int t = 0; t < 32; ++t) {
        float4 ev = e[t], zz = zb[t];
        zqb[t] = ev;
        float dx = ev.x - zz.x, dy = ev.y - zz.y, dz = ev.z - zz.z, dw = ev.w - zz.w;
        ss = fmaf(dx, dx, fmaf(dy, dy, fmaf(dz, dz, fmaf(dw, dw, ss))));
    }
    red[b] = ss;
    __syncthreads();
    for (int s = 128; s > 0; s >>= 1) {
        if (b < s) red[b] += red[b + s];
        __syncthreads();
    }
    if (b == 0) {
        float l = red[0] / 32768.f;
        out[3145728] = l;
        out[3145729] = l;
    }
}

// ------------------ Kernel D: decoder config-GEMMs + expand ------------------
__global__ __launch_bounds__(256) void k_decode(
    const float* __restrict__ zq, const float* __restrict__ Wcfg,
    const float* __restrict__ db1, const float* __restrict__ dw2,
    const float* __restrict__ db2, const float* __restrict__ dw3,
    const float* __restrict__ db3, float* __restrict__ out)
{
    __shared__ __align__(16) float zsh[128];
    __shared__ float d1e[64][10];    // 9 cfgs + zero slot
    __shared__ float d2e[64][26];    // 25 cfgs + zero slot
    __shared__ float o3[3 * 49];

    const int b = blockIdx.x, tid = threadIdx.x;
    if (tid < 128) zsh[tid] = zq[(size_t)b * 128 + tid];
    if (tid < 64) { d1e[tid][9] = 0.f; d2e[tid][25] = 0.f; }
    __syncthreads();

    // ---- stage 1: d1cfg[o][cfg] = relu(db1 + Wcfg[cfg][o][:] . zq) ----
    for (int id = tid; id < 576; id += 256) {
        int o = id / 9, cfg = id % 9;
        const float4* wv = (const float4*)(Wcfg + ((size_t)cfg * 64 + o) * 128);
        const float4* zv = (const float4*)zsh;
        float acc = db1[o];
        for (int t = 0; t < 32; ++t) {
            float4 w4 = wv[t], z4 = zv[t];
            acc = fmaf(w4.x, z4.x, acc);
            acc = fmaf(w4.y, z4.y, acc);
            acc = fmaf(w4.z, z4.z, acc);
            acc = fmaf(w4.w, z4.w, acc);
        }
        d1e[o][cfg] = fmaxf(acc, 0.f);
    }
    __syncthreads();

    // ---- stage 2: 25 cfgs; thread = (o, i-quarter); shfl reduce ----
    {
        const int TY5[5][3] = {{-1,0,1},{0,1,1},{1,1,1},{1,1,2},{1,2,-1}};
        const int o = tid >> 2, isub = tid & 3;
        float acc[25];
#pragma unroll
        for (int c = 0; c < 25; ++c) acc[c] = 0.f;
        for (int ii = 0; ii < 16; ++ii) {
            int i = isub + ii * 4;
            float d1v[10];
#pragma unroll
            for (int t = 0; t < 9; ++t) d1v[t] = d1e[i][t];
            d1v[9] = 0.f;
            float w9[9];
            const float* wp = dw2 + ((size_t)i * 64 + o) * 9;
#pragma unroll
            for (int t = 0; t < 9; ++t) w9[t] = wp[t];
#pragma unroll
            for (int cy = 0; cy < 5; ++cy) {
#pragma unroll
                for (int ky = 0; ky < 3; ++ky) {
                    int ty = TY5[cy][ky];
                    if (ty < 0) continue;
#pragma unroll
                    for (int cx = 0; cx < 5; ++cx) {
#pragma unroll
                        for (int kx = 0; kx < 3; ++kx) {
                            int tx = TY5[cx][kx];
                            if (tx < 0) continue;
                            acc[cy * 5 + cx] = fmaf(w9[(2 - ky) * 3 + (2 - kx)],
                                                    d1v[ty * 3 + tx], acc[cy * 5 + cx]);
                        }
                    }
                }
            }
        }
#pragma unroll
        for (int c = 0; c < 25; ++c) {
            float v = acc[c];
            v += __shfl_xor(v, 1);
            v += __shfl_xor(v, 2);
            if (isub == 0) d2e[o][c] = fmaxf(v + db2[o], 0.f);
        }
    }
    __syncthreads();

    // ---- stage 3: 49 cfgs x 3 channels ----
    if (tid < 147) {
        const int TY7[7][3] = {{-1,0,1},{0,1,2},{1,2,2},{2,2,2},{2,2,3},{2,3,4},{3,4,-1}};
        int c3 = tid / 49, cc = tid % 49, cy = cc / 7, cx = cc % 7;
        float acc = db3[c3];
        for (int i = 0; i < 64; ++i) {
            const float* wp = dw3 + ((size_t)i * 3 + c3) * 9;
#pragma unroll
            for (int ky = 0; ky < 3; ++ky) {
                int ty = TY7[cy][ky];
#pragma unroll
                for (int kx = 0; kx < 3; ++kx) {
                    int tx = TY7[cx][kx];
                    int t = (ty < 0 || tx < 0) ? 25 : ty * 5 + tx;
                    acc = fmaf(wp[(2 - ky) * 3 + (2 - kx)], d2e[i][t], acc);
                }
            }
        }
        o3[c3 * 49 + cc] = tanhf(acc);
    }
    __syncthreads();

    // ---- expand + float4 write ----
    float4* ob = (float4*)(out + (size_t)b * 3 * 4096);
    for (int id = tid; id < 3072; id += 256) {
        int base = id * 4;
        int c = base >> 12, rem = base & 4095, y = rem >> 6, x0 = rem & 63;
        int ry = (y <= 3) ? y : (y >= 60 ? y - 57 : 3);
        const float* row = &o3[c * 49 + ry * 7];
        float4 v;
        int x;
        x = x0 + 0; v.x = row[(x <= 3) ? x : (x >= 60 ? x - 57 : 3)];
        x = x0 + 1; v.y = row[(x <= 3) ? x : (x >= 60 ? x - 57 : 3)];
        x = x0 + 2; v.z = row[(x <= 3) ? x : (x >= 60 ? x - 57 : 3)];
        x = x0 + 3; v.w = row[(x <= 3) ? x : (x >= 60 ? x - 57 : 3)];
        ob[id] = v;
    }
}

// ---------------------------------------------------------------------------
extern "C" void kernel_launch(void* const* d_in, const int* in_sizes, int n_in,
                              void* d_out, int out_size, void* d_ws, size_t ws_size,
                              hipStream_t stream)
{
    const float* patch  = (const float*)d_in[0];
    const float* enc_w1 = (const float*)d_in[1];
    const float* enc_b1 = (const float*)d_in[2];
    const float* enc_w2 = (const float*)d_in[3];
    const float* enc_b2 = (const float*)d_in[4];
    const float* emb    = (const float*)d_in[5];
    const float* dec_w1 = (const float*)d_in[6];
    const float* dec_b1 = (const float*)d_in[7];
    const float* dec_w2 = (const float*)d_in[8];
    const float* dec_b2 = (const float*)d_in[9];
    const float* dec_w3 = (const float*)d_in[10];
    const float* dec_b3 = (const float*)d_in[11];

    float* out = (float*)d_out;
    float* ws  = (float*)d_ws;

    float* pstat = ws;                     // 1024*576 = 589824
    float* z     = ws + 589824;            // 32768
    float* zq    = ws + 622592;            // 32768
    float* pd2   = ws + 655360;            // 4096
    int*   pidx  = (int*)(ws + 659456);    // 4096
    float* Wcfg  = ws + 663552;            // 73728
    float* en2   = ws + 737280;            // 8192

    k_conv1_stats<<<dim3(1024), dim3(256), 0, stream>>>(patch, enc_w1, enc_b1, pstat);
    k_pre<<<dim3(320), dim3(256), 0, stream>>>(dec_w1, emb, Wcfg, en2);
    k_zred<<<dim3(256), dim3(256), 0, stream>>>(pstat, enc_w2, enc_b2, z);
    k_vq_partial<<<dim3(1024), dim3(256), 0, stream>>>(z, emb, en2, pd2, pidx);
    k_vq_final<<<dim3(1), dim3(256), 0, stream>>>(z, emb, pd2, pidx, zq, out);
    k_decode<<<dim3(256), dim3(256), 0, stream>>>(zq, Wcfg, dec_b1, dec_w2, dec_b2,
                                                  dec_w3, dec_b3, out);
}

// Round 3
// 131.317 us; speedup vs baseline: 1.6424x; 1.2141x over previous
//
#include <hip/hip_runtime.h>
#include <math.h>

// ---------------------------------------------------------------------------
// VQCodebook forward, MI355X. B=256, D=128, K=8192, fp32.  4 kernels:
//  K1 conv1+ReLU+window-stats (2048 blocks) + Wcfg/||e||^2 pre-work (320 blocks)
//  K2 stats reduce -> S -> z GEMM + ||z||^2            (256 blocks)
//  K3 VQ partial argmin, 16 batches x 512 codes/block  (256 blocks)
//  K4 final argmin + losses + decoder config-GEMMs + expand (256 blocks)
// ---------------------------------------------------------------------------

// ------------------ K1: conv1 + relu + partial stats, and pre-work ------------------
__global__ __launch_bounds__(256) void k_conv1_pre(
    const float* __restrict__ patch, const float* __restrict__ w1,
    const float* __restrict__ b1, const float* __restrict__ dw1,
    const float* __restrict__ emb, float* __restrict__ pstat,
    float* __restrict__ Wcfg, float* __restrict__ en2)
{
    __shared__ __align__(16) float lds[2304];
    const int blk = blockIdx.x;
    const int tid = threadIdx.x;

    if (blk >= 2048) {   // ---- pre-work blocks ----
        const int gid = (blk - 2048) * 256 + tid;
        if (gid < 73728) {
            const int cfg = gid >> 13;
            const int o = (gid >> 7) & 63;
            const int i = gid & 127;
            const int cy = cfg / 3, cx = cfg % 3;
            const int ylo = (cy == 2) ? 1 : 0, yhi = (cy == 0) ? 1 : 2;
            const int xlo = (cx == 2) ? 1 : 0, xhi = (cx == 0) ? 1 : 2;
            const float* wp = dw1 + ((size_t)i * 64 + o) * 9;
            float s = 0.f;
            for (int ky = ylo; ky <= yhi; ++ky)
                for (int kx = xlo; kx <= xhi; ++kx)
                    s += wp[ky * 3 + kx];
            Wcfg[gid] = s;
        } else if (gid < 81920) {
            const int k = gid - 73728;
            const float4* e = (const float4*)(emb + (size_t)k * 128);
            float s = 0.f;
            for (int t = 0; t < 32; ++t) {
                float4 v = e[t];
                s = fmaf(v.x, v.x, fmaf(v.y, v.y, fmaf(v.z, v.z, fmaf(v.w, v.w, s))));
            }
            en2[k] = s;
        }
        return;
    }

    // ---- conv blocks: 8 output rows each ----
    const int b = blk >> 3, rg = blk & 7;
    const int y0 = rg * 8;
    const float* pb = patch + (size_t)b * 12288;
    // padded layout: [ic][r:10][p:72], input x at p=x+3, row r holds y=y0+r-1
    for (int i = tid; i < 2160; i += 256) {
        const int c = i / 720, rem = i - c * 720;
        const int r = rem / 72, p = rem - r * 72;
        const int y = y0 + r - 1, x = p - 3;
        float v = 0.f;
        if (y >= 0 && y < 64 && x >= 0 && x < 64)
            v = pb[(c << 12) + (y << 6) + x];
        lds[i] = v;
    }
    __syncthreads();

    const int ch = tid & 63, q = tid >> 6;   // q: 2 rows each
    float w[3][3][3];
#pragma unroll
    for (int ic = 0; ic < 3; ++ic)
#pragma unroll
        for (int ky = 0; ky < 3; ++ky)
#pragma unroll
            for (int kx = 0; kx < 3; ++kx)
                w[ic][ky][kx] = w1[((ch * 3 + ic) * 3 + ky) * 3 + kx];
    const float bias = b1[ch];

    float T = 0, r0s = 0, r63s = 0, c0s = 0, c63s = 0;
    float h00 = 0, h063 = 0, h630 = 0, h6363 = 0;

#pragma unroll
    for (int sub = 0; sub < 2; ++sub) {
        const int yl = q * 2 + sub;
        const bool isr0  = (rg == 0) && (yl == 0);
        const bool isr63 = (rg == 7) && (yl == 7);
        float cr[3][3][2];   // sliding carry: p = xc*4+2, xc*4+3
#pragma unroll
        for (int ic = 0; ic < 3; ++ic)
#pragma unroll
            for (int ky = 0; ky < 3; ++ky) {
                const float2 t2 = *(const float2*)&lds[(ic * 10 + yl + ky) * 72 + 2];
                cr[ic][ky][0] = t2.x; cr[ic][ky][1] = t2.y;
            }
#pragma unroll 4
        for (int xc = 0; xc < 16; ++xc) {
            float a0 = bias, a1 = bias, a2 = bias, a3 = bias;
#pragma unroll
            for (int ic = 0; ic < 3; ++ic)
#pragma unroll
                for (int ky = 0; ky < 3; ++ky) {
                    const float4 nw = *(const float4*)&lds[(ic * 10 + yl + ky) * 72 + xc * 4 + 4];
                    const float w0 = w[ic][ky][0], w1v = w[ic][ky][1], w2v = w[ic][ky][2];
                    a0 = fmaf(w0, cr[ic][ky][0], fmaf(w1v, cr[ic][ky][1], fmaf(w2v, nw.x, a0)));
                    a1 = fmaf(w0, cr[ic][ky][1], fmaf(w1v, nw.x, fmaf(w2v, nw.y, a1)));
                    a2 = fmaf(w0, nw.x, fmaf(w1v, nw.y, fmaf(w2v, nw.z, a2)));
                    a3 = fmaf(w0, nw.y, fmaf(w1v, nw.z, fmaf(w2v, nw.w, a3)));
                    cr[ic][ky][0] = nw.z; cr[ic][ky][1] = nw.w;
                }
            a0 = fmaxf(a0, 0.f); a1 = fmaxf(a1, 0.f);
            a2 = fmaxf(a2, 0.f); a3 = fmaxf(a3, 0.f);
            const float rs = (a0 + a1) + (a2 + a3);
            T += rs;
            if (isr0)  { r0s += rs;  if (xc == 0) h00 = a0;  if (xc == 15) h063 = a3; }
            if (isr63) { r63s += rs; if (xc == 0) h630 = a0; if (xc == 15) h6363 = a3; }
            if (xc == 0)  c0s += a0;
            if (xc == 15) c63s += a3;
        }
    }
    __syncthreads();   // reuse lds for reduction
    float st[9] = {T, r0s, r63s, c0s, c63s, h00, h063, h630, h6363};
#pragma unroll
    for (int s = 0; s < 9; ++s) lds[(s * 4 + q) * 64 + ch] = st[s];
    __syncthreads();
    if (tid < 64) {
        float* pp = pstat + (size_t)blk * 576;
#pragma unroll
        for (int s = 0; s < 9; ++s)
            pp[s * 64 + tid] = lds[(s * 4 + 0) * 64 + tid] + lds[(s * 4 + 1) * 64 + tid]
                             + lds[(s * 4 + 2) * 64 + tid] + lds[(s * 4 + 3) * 64 + tid];
    }
}

// ------------------ K2: stats reduce + S + z-GEMM + ||z||^2 ------------------
__global__ __launch_bounds__(256) void k_zred(
    const float* __restrict__ pstat, const float* __restrict__ w2,
    const float* __restrict__ b2, float* __restrict__ z, float* __restrict__ zn2)
{
    __shared__ float fst[576];
    __shared__ __align__(16) float Ssh[576];
    __shared__ float zp[256];
    __shared__ float red2[128];
    const int b = blockIdx.x, tid = threadIdx.x;

    const float* pp = pstat + (size_t)b * 8 * 576;
    for (int i = tid; i < 576; i += 256) {
        float s = 0.f;
#pragma unroll
        for (int g = 0; g < 8; ++g) s += pp[g * 576 + i];
        fst[i] = s;
    }
    __syncthreads();

    if (tid < 64) {
        const int ch = tid;
        const float Tt   = fst[0 * 64 + ch], R0  = fst[1 * 64 + ch], R63 = fst[2 * 64 + ch];
        const float C0   = fst[3 * 64 + ch], C63 = fst[4 * 64 + ch];
        const float H00  = fst[5 * 64 + ch], H063 = fst[6 * 64 + ch];
        const float H630 = fst[7 * 64 + ch], H6363 = fst[8 * 64 + ch];
#pragma unroll
        for (int ky = 0; ky < 3; ++ky) {
            const float rex = (ky == 0) ? R63 : (ky == 2 ? R0 : 0.f);
#pragma unroll
            for (int kx = 0; kx < 3; ++kx) {
                const float cex = (kx == 0) ? C63 : (kx == 2 ? C0 : 0.f);
                float corner = 0.f;
                if (ky == 0 && kx == 0) corner = H6363;
                if (ky == 0 && kx == 2) corner = H630;
                if (ky == 2 && kx == 0) corner = H063;
                if (ky == 2 && kx == 2) corner = H00;
                Ssh[ch * 9 + ky * 3 + kx] = (Tt - rex - cex + corner) * (1.f / 4096.f);
            }
        }
    }
    __syncthreads();

    const int oc = tid & 127, h = tid >> 7;
    const float4* Wv = (const float4*)(w2 + (size_t)oc * 576 + h * 288);
    const float4* Sv = (const float4*)(Ssh + h * 288);
    float acc = 0.f;
    for (int t = 0; t < 72; ++t) {
        const float4 w4 = Wv[t], s4 = Sv[t];
        acc = fmaf(w4.x, s4.x, acc);
        acc = fmaf(w4.y, s4.y, acc);
        acc = fmaf(w4.z, s4.z, acc);
        acc = fmaf(w4.w, s4.w, acc);
    }
    zp[tid] = acc;
    __syncthreads();
    if (tid < 128) {
        const float zv = b2[tid] + zp[tid] + zp[tid + 128];
        z[(size_t)b * 128 + tid] = zv;
        red2[tid] = zv * zv;
    }
    __syncthreads();
    if (tid < 64) {
        float v = red2[tid] + red2[tid + 64];
        v += __shfl_xor(v, 32); v += __shfl_xor(v, 16); v += __shfl_xor(v, 8);
        v += __shfl_xor(v, 4);  v += __shfl_xor(v, 2);  v += __shfl_xor(v, 1);
        if (tid == 0) zn2[b] = v;
    }
}

// ------------------ K3: VQ partial argmin (16 bg x 16 kc) ------------------
__global__ __launch_bounds__(256) void k_vq(
    const float* __restrict__ z, const float* __restrict__ emb,
    const float* __restrict__ en2, float* __restrict__ pd2, int* __restrict__ pidx)
{
    __shared__ __align__(16) float zsh[2048];
    __shared__ float wd[16][4];
    __shared__ int   wi[16][4];
    const int tid = threadIdx.x;
    const int bg = blockIdx.x >> 4, kc = blockIdx.x & 15;
    const int b0 = bg * 16;
    for (int i = tid; i < 2048; i += 256) zsh[i] = z[(size_t)b0 * 128 + i];
    __syncthreads();

    const int k0 = kc * 512 + tid, k1 = k0 + 256;
    const float4* e0 = (const float4*)(emb + (size_t)k0 * 128);
    const float4* e1 = (const float4*)(emb + (size_t)k1 * 128);
    const float4* zv = (const float4*)zsh;

    float acc0[16], acc1[16];
#pragma unroll
    for (int bb = 0; bb < 16; ++bb) { acc0[bb] = 0.f; acc1[bb] = 0.f; }

    for (int t = 0; t < 32; ++t) {
        const float4 ea = e0[t], eb = e1[t];
#pragma unroll
        for (int bb = 0; bb < 16; ++bb) {
            const float4 zz = zv[bb * 32 + t];
            acc0[bb] = fmaf(zz.x, ea.x, fmaf(zz.y, ea.y, fmaf(zz.z, ea.z, fmaf(zz.w, ea.w, acc0[bb]))));
            acc1[bb] = fmaf(zz.x, eb.x, fmaf(zz.y, eb.y, fmaf(zz.z, eb.z, fmaf(zz.w, eb.w, acc1[bb]))));
        }
    }
    const float E0 = en2[k0], E1 = en2[k1];
    const int wv_ = tid >> 6, ln = tid & 63;
#pragma unroll
    for (int bb = 0; bb < 16; ++bb) {
        const float da = fmaf(-2.f, acc0[bb], E0);
        const float db = fmaf(-2.f, acc1[bb], E1);
        float d; int ix;
        if (da <= db) { d = da; ix = k0; } else { d = db; ix = k1; }
#pragma unroll
        for (int off = 32; off > 0; off >>= 1) {
            const float od = __shfl_xor(d, off);
            const int   oi = __shfl_xor(ix, off);
            if (od < d || (od == d && oi < ix)) { d = od; ix = oi; }
        }
        if (ln == 0) { wd[bb][wv_] = d; wi[bb][wv_] = ix; }
    }
    __syncthreads();
    if (tid < 16) {
        float d = wd[tid][0]; int ix = wi[tid][0];
#pragma unroll
        for (int wv2 = 1; wv2 < 4; ++wv2) {
            const float od = wd[tid][wv2]; const int oi = wi[tid][wv2];
            if (od < d || (od == d && oi < ix)) { d = od; ix = oi; }
        }
        pd2[(b0 + tid) * 16 + kc] = d;
        pidx[(b0 + tid) * 16 + kc] = ix;
    }
}

// ------------------ K4: final argmin + losses + decoder + expand ------------------
__global__ __launch_bounds__(256) void k_decode(
    const float* __restrict__ emb, const float* __restrict__ zn2,
    const float* __restrict__ pd2, const int* __restrict__ pidx,
    const float* __restrict__ Wcfg, const float* __restrict__ db1,
    const float* __restrict__ dw2, const float* __restrict__ db2,
    const float* __restrict__ dw3, const float* __restrict__ db3,
    float* __restrict__ out)
{
    __shared__ __align__(16) float zsh[128];
    __shared__ float d1e[64][10];
    __shared__ float d2e[64][26];
    __shared__ float o3[3 * 49];
    __shared__ int   bisld[256];
    __shared__ float redl[256];

    const int b = blockIdx.x, tid = threadIdx.x;

    // ---- phase 0: per-batch final argmin (thread t = batch t), all blocks ----
    float dmin = pd2[tid * 16]; int bi = pidx[tid * 16];
    for (int j = 1; j < 16; ++j) {
        const float d = pd2[tid * 16 + j]; const int ix = pidx[tid * 16 + j];
        if (d < dmin || (d == dmin && ix < bi)) { dmin = d; bi = ix; }
    }
    bisld[tid] = bi;
    redl[tid] = dmin + zn2[tid];   // ||z-e||^2 = (||e||^2 - 2 z.e) + ||z||^2
    __syncthreads();

    const int mybi = bisld[b];
    if (tid < 128) { zsh[tid] = emb[(size_t)mybi * 128 + tid]; redl[tid] += redl[tid + 128]; }
    if (tid >= 128 && tid < 192) { d1e[tid - 128][9] = 0.f; d2e[tid - 128][25] = 0.f; }
    __syncthreads();
    if (tid < 64) {
        float v = redl[tid] + redl[tid + 64];
        v += __shfl_xor(v, 32); v += __shfl_xor(v, 16); v += __shfl_xor(v, 8);
        v += __shfl_xor(v, 4);  v += __shfl_xor(v, 2);  v += __shfl_xor(v, 1);
        if (tid == 0 && b == 0) {
            const float L = v * (1.f / 32768.f);
            out[3145728] = L;
            out[3145729] = L;
        }
    }
    if (b == 0) out[3145730 + tid] = (float)bisld[tid];

    // ---- stage 1: d1cfg[o][cfg] = relu(db1 + Wcfg[cfg][o][:] . zq) ----
    for (int id = tid; id < 576; id += 256) {
        const int o = id / 9, cfg = id % 9;
        const float4* wv = (const float4*)(Wcfg + ((size_t)cfg * 64 + o) * 128);
        const float4* zv = (const float4*)zsh;
        float acc = db1[o];
        for (int t = 0; t < 32; ++t) {
            const float4 w4 = wv[t], z4 = zv[t];
            acc = fmaf(w4.x, z4.x, acc);
            acc = fmaf(w4.y, z4.y, acc);
            acc = fmaf(w4.z, z4.z, acc);
            acc = fmaf(w4.w, z4.w, acc);
        }
        d1e[o][cfg] = fmaxf(acc, 0.f);
    }
    __syncthreads();

    // ---- stage 2: 25 cfgs; thread = (o, i-quarter); shfl reduce ----
    {
        const int TY5[5][3] = {{-1,0,1},{0,1,1},{1,1,1},{1,1,2},{1,2,-1}};
        const int o = tid >> 2, isub = tid & 3;
        float acc[25];
#pragma unroll
        for (int c = 0; c < 25; ++c) acc[c] = 0.f;
        for (int ii = 0; ii < 16; ++ii) {
            const int i = isub + ii * 4;
            float d1v[10];
#pragma unroll
            for (int t = 0; t < 9; ++t) d1v[t] = d1e[i][t];
            d1v[9] = 0.f;
            float w9[9];
            const float* wp = dw2 + ((size_t)i * 64 + o) * 9;
#pragma unroll
            for (int t = 0; t < 9; ++t) w9[t] = wp[t];
#pragma unroll
            for (int cy = 0; cy < 5; ++cy) {
#pragma unroll
                for (int ky = 0; ky < 3; ++ky) {
                    const int ty = TY5[cy][ky];
                    if (ty < 0) continue;
#pragma unroll
                    for (int cx = 0; cx < 5; ++cx) {
#pragma unroll
                        for (int kx = 0; kx < 3; ++kx) {
                            const int tx = TY5[cx][kx];
                            if (tx < 0) continue;
                            acc[cy * 5 + cx] = fmaf(w9[(2 - ky) * 3 + (2 - kx)],
                                                    d1v[ty * 3 + tx], acc[cy * 5 + cx]);
                        }
                    }
                }
            }
        }
#pragma unroll
        for (int c = 0; c < 25; ++c) {
            float v = acc[c];
            v += __shfl_xor(v, 1);
            v += __shfl_xor(v, 2);
            if (isub == 0) d2e[o][c] = fmaxf(v + db2[o], 0.f);
        }
    }
    __syncthreads();

    // ---- stage 3: 49 cfgs x 3 channels ----
    if (tid < 147) {
        const int TY7[7][3] = {{-1,0,1},{0,1,2},{1,2,2},{2,2,2},{2,2,3},{2,3,4},{3,4,-1}};
        const int c3 = tid / 49, cc = tid % 49, cy = cc / 7, cx = cc % 7;
        float acc = db3[c3];
        for (int i = 0; i < 64; ++i) {
            const float* wp = dw3 + ((size_t)i * 3 + c3) * 9;
#pragma unroll
            for (int ky = 0; ky < 3; ++ky) {
                const int ty = TY7[cy][ky];
#pragma unroll
                for (int kx = 0; kx < 3; ++kx) {
                    const int tx = TY7[cx][kx];
                    const int t = (ty < 0 || tx < 0) ? 25 : ty * 5 + tx;
                    acc = fmaf(wp[(2 - ky) * 3 + (2 - kx)], d2e[i][t], acc);
                }
            }
        }
        o3[c3 * 49 + cc] = tanhf(acc);
    }
    __syncthreads();

    // ---- expand + float4 write ----
    float4* ob = (float4*)(out + (size_t)b * 12288);
    for (int id = tid; id < 3072; id += 256) {
        const int base = id * 4;
        const int c = base >> 12, rem = base & 4095, y = rem >> 6, x0 = rem & 63;
        const int ry = (y <= 3) ? y : (y >= 60 ? y - 57 : 3);
        const float* row = &o3[c * 49 + ry * 7];
        float4 v;
        int x;
        x = x0 + 0; v.x = row[(x <= 3) ? x : (x >= 60 ? x - 57 : 3)];
        x = x0 + 1; v.y = row[(x <= 3) ? x : (x >= 60 ? x - 57 : 3)];
        x = x0 + 2; v.z = row[(x <= 3) ? x : (x >= 60 ? x - 57 : 3)];
        x = x0 + 3; v.w = row[(x <= 3) ? x : (x >= 60 ? x - 57 : 3)];
        ob[id] = v;
    }
}

// ---------------------------------------------------------------------------
extern "C" void kernel_launch(void* const* d_in, const int* in_sizes, int n_in,
                              void* d_out, int out_size, void* d_ws, size_t ws_size,
                              hipStream_t stream)
{
    const float* patch  = (const float*)d_in[0];
    const float* enc_w1 = (const float*)d_in[1];
    const float* enc_b1 = (const float*)d_in[2];
    const float* enc_w2 = (const float*)d_in[3];
    const float* enc_b2 = (const float*)d_in[4];
    const float* emb    = (const float*)d_in[5];
    const float* dec_w1 = (const float*)d_in[6];
    const float* dec_b1 = (const float*)d_in[7];
    const float* dec_w2 = (const float*)d_in[8];
    const float* dec_b2 = (const float*)d_in[9];
    const float* dec_w3 = (const float*)d_in[10];
    const float* dec_b3 = (const float*)d_in[11];

    float* out = (float*)d_out;
    float* ws  = (float*)d_ws;

    float* pstat = ws;                       // 2048*576 = 1179648
    float* z     = ws + 1179648;             // 32768
    float* zn2   = ws + 1212416;             // 256
    float* pd2   = ws + 1212672;             // 4096
    int*   pidx  = (int*)(ws + 1216768);     // 4096
    float* Wcfg  = ws + 1220864;             // 73728
    float* en2   = ws + 1294592;             // 8192   (total 5.2 MB)

    k_conv1_pre<<<dim3(2368), dim3(256), 0, stream>>>(patch, enc_w1, enc_b1, dec_w1,
                                                      emb, pstat, Wcfg, en2);
    k_zred<<<dim3(256), dim3(256), 0, stream>>>(pstat, enc_w2, enc_b2, z, zn2);
    k_vq<<<dim3(256), dim3(256), 0, stream>>>(z, emb, en2, pd2, pidx);
    k_decode<<<dim3(256), dim3(256), 0, stream>>>(emb, zn2, pd2, pidx, Wcfg, dec_b1,
                                                  dec_w2, dec_b2, dec_w3, dec_b3, out);
}